// Round 2
// baseline (270.585 us; speedup 1.0000x reference)
//
#include <hip/hip_runtime.h>
#include <hip/hip_bf16.h>

#define N_ROWS 4096
#define C_CLS  1000
#define C_PAD  1024
#define A_DIM  2048

typedef __attribute__((ext_vector_type(8))) short short8;
typedef __attribute__((ext_vector_type(4))) float f32x4;

__device__ __forceinline__ unsigned short f2bf(float x) {
    unsigned u = __float_as_uint(x);
    unsigned rounding = 0x7fffu + ((u >> 16) & 1u);
    return (unsigned short)((u + rounding) >> 16);
}

__device__ __forceinline__ unsigned pack2(float a, float b) {
    return (unsigned)f2bf(a) | ((unsigned)f2bf(b) << 16);
}

// async global->LDS, 16B per lane; lds dst must be wave-uniform base (HW adds lane*16)
__device__ __forceinline__ void gload16(unsigned short* lds, const unsigned short* g) {
    __builtin_amdgcn_global_load_lds(
        (const __attribute__((address_space(1))) unsigned int*)g,
        (__attribute__((address_space(3))) unsigned int*)lds,
        16, 0, 0);
}

// ---------------- fused prep: blocks [0,4096) do per-row A-operands,
//                  blocks [4096,5120) do W/W^2 bf16 conversion --------------
__global__ __launch_bounds__(256) void prep_all(
        const float* __restrict__ F, const float* __restrict__ CV,
        const float* __restrict__ W, const int* __restrict__ labels,
        const float* __restrict__ ratio_p,
        unsigned short* __restrict__ Fb, unsigned short* __restrict__ Ub,
        unsigned short* __restrict__ Vb,
        unsigned short* __restrict__ Wb, unsigned short* __restrict__ W2b,
        float* __restrict__ t3c, float* __restrict__ out_loss) {
    int bid = blockIdx.x;
    if (bid >= N_ROWS) {
        // ---- W prep: 8 elems/thread ----
        if (bid == N_ROWS && threadIdx.x == 0) out_loss[0] = 0.f;
        int t = (bid - N_ROWS) * 256 + threadIdx.x;
        int a8 = t * 8;
        int c = a8 >> 11;            // / 2048
        int a = a8 & (A_DIM - 1);
        float4 w0 = make_float4(0.f, 0.f, 0.f, 0.f);
        float4 w1 = make_float4(0.f, 0.f, 0.f, 0.f);
        if (c < C_CLS) {
            w0 = *(const float4*)(W + (size_t)c * A_DIM + a);
            w1 = *(const float4*)(W + (size_t)c * A_DIM + a + 4);
        }
        uint4 pw, pw2;
        pw.x  = pack2(w0.x, w0.y);  pw.y  = pack2(w0.z, w0.w);
        pw.z  = pack2(w1.x, w1.y);  pw.w  = pack2(w1.z, w1.w);
        pw2.x = pack2(w0.x*w0.x, w0.y*w0.y);  pw2.y = pack2(w0.z*w0.z, w0.w*w0.w);
        pw2.z = pack2(w1.x*w1.x, w1.y*w1.y);  pw2.w = pack2(w1.z*w1.z, w1.w*w1.w);
        *(uint4*)(Wb  + (size_t)a8) = pw;
        *(uint4*)(W2b + (size_t)a8) = pw2;
        return;
    }
    // ---- per-row A-operand prep ----
    int n = bid;
    int y = labels[n];
    float ratio = ratio_p[0];
    float hr = 0.5f * ratio;
    const float* frow  = F  + (size_t)n * A_DIM;
    const float* cvrow = CV + (size_t)n * A_DIM;
    const float* wyrow = W  + (size_t)y * A_DIM;
    size_t obase = (size_t)n * A_DIM;

    int a = threadIdx.x * 8;
    float4 f0  = *(const float4*)(frow + a);
    float4 f1  = *(const float4*)(frow + a + 4);
    float4 c0  = *(const float4*)(cvrow + a);
    float4 c1  = *(const float4*)(cvrow + a + 4);
    float4 y0  = *(const float4*)(wyrow + a);
    float4 y1  = *(const float4*)(wyrow + a + 4);

    float s = y0.x*y0.x*c0.x + y0.y*y0.y*c0.y + y0.z*y0.z*c0.z + y0.w*y0.w*c0.w
            + y1.x*y1.x*c1.x + y1.y*y1.y*c1.y + y1.z*y1.z*c1.z + y1.w*y1.w*c1.w;

    uint4 pf, pu, pv;
    pf.x = pack2(f0.x, f0.y);  pf.y = pack2(f0.z, f0.w);
    pf.z = pack2(f1.x, f1.y);  pf.w = pack2(f1.z, f1.w);
    pu.x = pack2(f0.x - ratio*c0.x*y0.x, f0.y - ratio*c0.y*y0.y);
    pu.y = pack2(f0.z - ratio*c0.z*y0.z, f0.w - ratio*c0.w*y0.w);
    pu.z = pack2(f1.x - ratio*c1.x*y1.x, f1.y - ratio*c1.y*y1.y);
    pu.w = pack2(f1.z - ratio*c1.z*y1.z, f1.w - ratio*c1.w*y1.w);
    pv.x = pack2(hr*c0.x, hr*c0.y);  pv.y = pack2(hr*c0.z, hr*c0.w);
    pv.z = pack2(hr*c1.x, hr*c1.y);  pv.w = pack2(hr*c1.z, hr*c1.w);
    *(uint4*)(Fb + obase + a) = pf;
    *(uint4*)(Ub + obase + a) = pu;
    *(uint4*)(Vb + obase + a) = pv;

    for (int off = 32; off; off >>= 1) s += __shfl_down(s, off);
    __shared__ float wsum[4];
    int lane = threadIdx.x & 63, wid = threadIdx.x >> 6;
    if (lane == 0) wsum[wid] = s;
    __syncthreads();
    if (threadIdx.x == 0)
        t3c[n] = hr * (wsum[0] + wsum[1] + wsum[2] + wsum[3]);
}

// ---------------- fused triple-GEMM: logits + aug ---------------------------
#define BM 128
#define BN 64
#define BK 32

__global__ __launch_bounds__(256, 2) void gemm_fused(
        const unsigned short* __restrict__ Fb, const unsigned short* __restrict__ Ub,
        const unsigned short* __restrict__ Vb, const unsigned short* __restrict__ Wb,
        const unsigned short* __restrict__ W2b,
        const float* __restrict__ t3c, const float* __restrict__ bias,
        float* __restrict__ out_logits, float* __restrict__ aug) {
    __shared__ unsigned short sF[BM * BK];
    __shared__ unsigned short sU[BM * BK];
    __shared__ unsigned short sV[BM * BK];
    __shared__ unsigned short sW[BN * BK];
    __shared__ unsigned short sW2[BN * BK];

    // XCD-bijective swizzle: 512 blocks, 64 per XCD; each XCD owns 2 bn-strips
    int wg = blockIdx.x;
    int xcd = wg & 7, idx = wg >> 3;          // idx in [0,64)
    int bn = (xcd << 1) | (idx >> 5);         // [0,16)
    int bm = idx & 31;                        // [0,32)

    int tid = threadIdx.x;
    int lane = tid & 63, wid = tid >> 6;
    int wm = wid >> 1, wn = wid & 1;          // 2x2 wave grid; wave tile 64x32

    // staging: per issue, 4 waves cover 64 rows (16 rows/wave, 4 lanes/row of 16B)
    int srow = lane >> 2;                                 // row within 16-row group
    int scs = ((lane & 3) * 8) ^ (((srow >> 1) & 3) << 3); // swizzled col (ushorts)
    int r0 = wid * 16 + srow;
    size_t ga0 = (size_t)(bm * BM + r0) * A_DIM + scs;      // A rows [0,64)
    size_t ga1 = ga0 + (size_t)64 * A_DIM;                  // A rows [64,128)
    size_t gb  = (size_t)(bn * BN + r0) * A_DIM + scs;      // B rows [0,64)
    int d0 = wid * 512;          // wave-uniform LDS chunk (ushorts), issue 0
    int d1 = 2048 + wid * 512;   // issue 1

    // fragment read addressing (swizzled, conflict-free)
    int fr = lane & 15;
    int kof = ((lane >> 4) * 8) ^ (((fr >> 1) & 3) << 3);
    int aoff = fr * BK + kof;

    f32x4 accL[4][2] = {};
    f32x4 accA[4][2] = {};

    for (int k0 = 0; k0 < A_DIM; k0 += BK) {
        __syncthreads();
        gload16(sF + d0, Fb + ga0);   gload16(sF + d1, Fb + ga1);
        gload16(sU + d0, Ub + ga0);   gload16(sU + d1, Ub + ga1);
        gload16(sV + d0, Vb + ga0);   gload16(sV + d1, Vb + ga1);
        gload16(sW + d0, Wb + gb);    gload16(sW2 + d0, W2b + gb);
        ga0 += BK; ga1 += BK; gb += BK;
        __syncthreads();

        short8 aF[4], aU[4], aV[4], bWf[2], bW2f[2];
        #pragma unroll
        for (int m = 0; m < 4; m++) {
            int off = wm * 2048 + m * 512 + aoff;
            aF[m] = *(const short8*)(sF + off);
            aU[m] = *(const short8*)(sU + off);
            aV[m] = *(const short8*)(sV + off);
        }
        #pragma unroll
        for (int n = 0; n < 2; n++) {
            int off = wn * 1024 + n * 512 + aoff;
            bWf[n]  = *(const short8*)(sW + off);
            bW2f[n] = *(const short8*)(sW2 + off);
        }
        #pragma unroll
        for (int m = 0; m < 4; m++)
            #pragma unroll
            for (int n = 0; n < 2; n++) {
                accL[m][n] = __builtin_amdgcn_mfma_f32_16x16x32_bf16(aF[m], bWf[n],  accL[m][n], 0, 0, 0);
                accA[m][n] = __builtin_amdgcn_mfma_f32_16x16x32_bf16(aU[m], bWf[n],  accA[m][n], 0, 0, 0);
                accA[m][n] = __builtin_amdgcn_mfma_f32_16x16x32_bf16(aV[m], bW2f[n], accA[m][n], 0, 0, 0);
            }
    }

    // epilogue
    #pragma unroll
    for (int n = 0; n < 2; n++) {
        int col = bn * BN + wn * 32 + n * 16 + fr;
        if (col < C_CLS) {
            float bv = bias[col];
            #pragma unroll
            for (int m = 0; m < 4; m++) {
                int rbase = bm * BM + wm * 64 + m * 16 + (lane >> 4) * 4;
                #pragma unroll
                for (int j = 0; j < 4; j++) {
                    int row = rbase + j;
                    out_logits[(size_t)row * C_CLS + col] = accL[m][n][j] + bv;
                    aug[(size_t)row * C_PAD + col] = accA[m][n][j] + bv + t3c[row];
                }
            }
        }
    }
}

// ---------------- per-row softmax NLL + atomic mean -------------------------
__global__ __launch_bounds__(256) void softmax_nll(const float* __restrict__ aug,
                                                   const int* __restrict__ labels,
                                                   float* __restrict__ out_loss) {
    int n = blockIdx.x;
    const float* row = aug + (size_t)n * C_PAD;
    int lane = threadIdx.x & 63, wid = threadIdx.x >> 6;
    __shared__ float sm[4], ss[4];

    float mx = -1e30f;
    for (int c = threadIdx.x; c < C_CLS; c += 256) mx = fmaxf(mx, row[c]);
    for (int off = 32; off; off >>= 1) mx = fmaxf(mx, __shfl_down(mx, off));
    if (lane == 0) sm[wid] = mx;
    __syncthreads();
    mx = fmaxf(fmaxf(sm[0], sm[1]), fmaxf(sm[2], sm[3]));

    float s = 0.f;
    for (int c = threadIdx.x; c < C_CLS; c += 256) s += __expf(row[c] - mx);
    for (int off = 32; off; off >>= 1) s += __shfl_down(s, off);
    if (lane == 0) ss[wid] = s;
    __syncthreads();
    if (threadIdx.x == 0) {
        float tot = ss[0] + ss[1] + ss[2] + ss[3];
        float nll = logf(tot) + mx - row[labels[n]];
        atomicAdd(out_loss, nll * (1.0f / (float)N_ROWS));
    }
}

// ---------------- launch -----------------------------------------------------
extern "C" void kernel_launch(void* const* d_in, const int* in_sizes, int n_in,
                              void* d_out, int out_size, void* d_ws, size_t ws_size,
                              hipStream_t stream) {
    const float* features = (const float*)d_in[0];
    const int*   labels   = (const int*)d_in[1];
    const float* cv       = (const float*)d_in[2];
    const float* ratio    = (const float*)d_in[3];
    const float* weight   = (const float*)d_in[4];
    const float* bias     = (const float*)d_in[5];
    float* out = (float*)d_out;

    char* p = (char*)d_ws;
    unsigned short* Wb  = (unsigned short*)p; p += (size_t)C_PAD * A_DIM * 2;
    unsigned short* W2b = (unsigned short*)p; p += (size_t)C_PAD * A_DIM * 2;
    unsigned short* Fb  = (unsigned short*)p; p += (size_t)N_ROWS * A_DIM * 2;
    unsigned short* Ub  = (unsigned short*)p; p += (size_t)N_ROWS * A_DIM * 2;
    unsigned short* Vb  = (unsigned short*)p; p += (size_t)N_ROWS * A_DIM * 2;
    float* t3c = (float*)p; p += (size_t)N_ROWS * 4;
    float* aug = (float*)p; p += (size_t)N_ROWS * C_PAD * 4;

    int wprep_blocks = (C_PAD * A_DIM / 8) / 256;  // 1024
    prep_all<<<N_ROWS + wprep_blocks, 256, 0, stream>>>(
        features, cv, weight, labels, ratio, Fb, Ub, Vb, Wb, W2b, t3c, out);
    gemm_fused<<<(C_PAD / BN) * (N_ROWS / BM), 256, 0, stream>>>(
        Fb, Ub, Vb, Wb, W2b, t3c, bias, out + 1, aug);
    softmax_nll<<<N_ROWS, 256, 0, stream>>>(aug, labels, out);
}

// Round 3
// 243.374 us; speedup vs baseline: 1.1118x; 1.1118x over previous
//
#include <hip/hip_runtime.h>
#include <hip/hip_bf16.h>

#define N_ROWS 4096
#define C_CLS  1000
#define C_PAD  1024
#define A_DIM  2048

typedef __attribute__((ext_vector_type(8))) short short8;
typedef __attribute__((ext_vector_type(4))) float f32x4;

__device__ __forceinline__ unsigned short f2bf(float x) {
    unsigned u = __float_as_uint(x);
    unsigned rounding = 0x7fffu + ((u >> 16) & 1u);
    return (unsigned short)((u + rounding) >> 16);
}

__device__ __forceinline__ unsigned pack2(float a, float b) {
    return (unsigned)f2bf(a) | ((unsigned)f2bf(b) << 16);
}

// async global->LDS, 16B per lane; lds dst is wave-uniform base (HW adds lane*16)
__device__ __forceinline__ void gload16(unsigned short* lds, const unsigned short* g) {
    __builtin_amdgcn_global_load_lds(
        (const __attribute__((address_space(1))) unsigned int*)g,
        (__attribute__((address_space(3))) unsigned int*)lds,
        16, 0, 0);
}

// ---------------- fused prep: blocks [0,4096) per-row A-operands,
//                  blocks [4096,5120) W/W^2 bf16 conversion ------------------
__global__ __launch_bounds__(256) void prep_all(
        const float* __restrict__ F, const float* __restrict__ CV,
        const float* __restrict__ W, const int* __restrict__ labels,
        const float* __restrict__ ratio_p,
        unsigned short* __restrict__ Fb, unsigned short* __restrict__ Ub,
        unsigned short* __restrict__ Vb,
        unsigned short* __restrict__ Wb, unsigned short* __restrict__ W2b,
        float* __restrict__ t3c) {
    int bid = blockIdx.x;
    if (bid >= N_ROWS) {
        int t = (bid - N_ROWS) * 256 + threadIdx.x;
        int a8 = t * 8;
        int c = a8 >> 11;
        int a = a8 & (A_DIM - 1);
        float4 w0 = make_float4(0.f, 0.f, 0.f, 0.f);
        float4 w1 = make_float4(0.f, 0.f, 0.f, 0.f);
        if (c < C_CLS) {
            w0 = *(const float4*)(W + (size_t)c * A_DIM + a);
            w1 = *(const float4*)(W + (size_t)c * A_DIM + a + 4);
        }
        uint4 pw, pw2;
        pw.x  = pack2(w0.x, w0.y);  pw.y  = pack2(w0.z, w0.w);
        pw.z  = pack2(w1.x, w1.y);  pw.w  = pack2(w1.z, w1.w);
        pw2.x = pack2(w0.x*w0.x, w0.y*w0.y);  pw2.y = pack2(w0.z*w0.z, w0.w*w0.w);
        pw2.z = pack2(w1.x*w1.x, w1.y*w1.y);  pw2.w = pack2(w1.z*w1.z, w1.w*w1.w);
        *(uint4*)(Wb  + (size_t)a8) = pw;
        *(uint4*)(W2b + (size_t)a8) = pw2;
        return;
    }
    int n = bid;
    int y = labels[n];
    float ratio = ratio_p[0];
    float hr = 0.5f * ratio;
    const float* frow  = F  + (size_t)n * A_DIM;
    const float* cvrow = CV + (size_t)n * A_DIM;
    const float* wyrow = W  + (size_t)y * A_DIM;
    size_t obase = (size_t)n * A_DIM;

    int a = threadIdx.x * 8;
    float4 f0  = *(const float4*)(frow + a);
    float4 f1  = *(const float4*)(frow + a + 4);
    float4 c0  = *(const float4*)(cvrow + a);
    float4 c1  = *(const float4*)(cvrow + a + 4);
    float4 y0  = *(const float4*)(wyrow + a);
    float4 y1  = *(const float4*)(wyrow + a + 4);

    float s = y0.x*y0.x*c0.x + y0.y*y0.y*c0.y + y0.z*y0.z*c0.z + y0.w*y0.w*c0.w
            + y1.x*y1.x*c1.x + y1.y*y1.y*c1.y + y1.z*y1.z*c1.z + y1.w*y1.w*c1.w;

    uint4 pf, pu, pv;
    pf.x = pack2(f0.x, f0.y);  pf.y = pack2(f0.z, f0.w);
    pf.z = pack2(f1.x, f1.y);  pf.w = pack2(f1.z, f1.w);
    pu.x = pack2(f0.x - ratio*c0.x*y0.x, f0.y - ratio*c0.y*y0.y);
    pu.y = pack2(f0.z - ratio*c0.z*y0.z, f0.w - ratio*c0.w*y0.w);
    pu.z = pack2(f1.x - ratio*c1.x*y1.x, f1.y - ratio*c1.y*y1.y);
    pu.w = pack2(f1.z - ratio*c1.z*y1.z, f1.w - ratio*c1.w*y1.w);
    pv.x = pack2(hr*c0.x, hr*c0.y);  pv.y = pack2(hr*c0.z, hr*c0.w);
    pv.z = pack2(hr*c1.x, hr*c1.y);  pv.w = pack2(hr*c1.z, hr*c1.w);
    *(uint4*)(Fb + obase + a) = pf;
    *(uint4*)(Ub + obase + a) = pu;
    *(uint4*)(Vb + obase + a) = pv;

    for (int off = 32; off; off >>= 1) s += __shfl_down(s, off);
    __shared__ float wsum[4];
    int lane = threadIdx.x & 63, wid = threadIdx.x >> 6;
    if (lane == 0) wsum[wid] = s;
    __syncthreads();
    if (threadIdx.x == 0)
        t3c[n] = hr * (wsum[0] + wsum[1] + wsum[2] + wsum[3]);
}

// ---------------- fused triple-GEMM: logits + aug ---------------------------
#define BM 128
#define BN 128
#define BK 32
#define TILE_USH (BM * BK)            // 4096 ushorts per matrix tile
#define BUF_USH  (5 * TILE_USH)       // 20480 ushorts per stage buffer
#define NT       (A_DIM / BK)         // 64 K-steps

__global__ __launch_bounds__(256, 1) void gemm_fused(
        const unsigned short* __restrict__ Fb, const unsigned short* __restrict__ Ub,
        const unsigned short* __restrict__ Vb, const unsigned short* __restrict__ Wb,
        const unsigned short* __restrict__ W2b,
        const float* __restrict__ t3c, const float* __restrict__ bias,
        float* __restrict__ out_logits, float* __restrict__ aug) {
    __shared__ unsigned short lds[2 * BUF_USH];   // 80 KiB, double-buffered

    // grid 256 = 32 bm x 8 bn; bn = bid&7 pins each bn-strip to one XCD
    int bid = blockIdx.x;
    int bn = bid & 7;
    int bm = bid >> 3;

    int tid = threadIdx.x;
    int lane = tid & 63, wid = tid >> 6;
    int wm = wid >> 1, wn = wid & 1;          // 2x2 wave grid; wave tile 64x64

    // staging addressing: wave covers 16 rows x 32 cols (1KB) per issue
    int srow = lane >> 2;                                  // 0..15
    int scs  = ((lane & 3) * 8) ^ (((srow >> 1) & 3) << 3); // swizzled col (ushorts)
    int r0 = wid * 16 + srow;
    size_t gA0 = (size_t)(bm * BM + r0) * A_DIM + scs;
    size_t gB0 = (size_t)(bn * BN + r0) * A_DIM + scs;
    const size_t gStep = (size_t)64 * A_DIM;               // second 64-row group
    int d0 = wid * 512;                                    // LDS chunk, issue 0
    int d1 = 2048 + wid * 512;                             // issue 1

    // fragment read addressing (same XOR as staging -> conflict-free)
    int fr = lane & 15;
    int kof = ((lane >> 4) * 8) ^ (((fr >> 1) & 3) << 3);
    int aoff = fr * BK + kof;

    f32x4 accL[4][4] = {};
    f32x4 accA[4][4] = {};

    // prologue: stage tile 0 into buffer 0
    {
        unsigned short* b = lds;
        gload16(b + 0*TILE_USH + d0, Fb  + gA0);
        gload16(b + 0*TILE_USH + d1, Fb  + gA0 + gStep);
        gload16(b + 1*TILE_USH + d0, Ub  + gA0);
        gload16(b + 1*TILE_USH + d1, Ub  + gA0 + gStep);
        gload16(b + 2*TILE_USH + d0, Vb  + gA0);
        gload16(b + 2*TILE_USH + d1, Vb  + gA0 + gStep);
        gload16(b + 3*TILE_USH + d0, Wb  + gB0);
        gload16(b + 3*TILE_USH + d1, Wb  + gB0 + gStep);
        gload16(b + 4*TILE_USH + d0, W2b + gB0);
        gload16(b + 4*TILE_USH + d1, W2b + gB0 + gStep);
    }
    __syncthreads();

    for (int t = 0; t < NT; t++) {
        unsigned short* cbuf = lds + (t & 1) * BUF_USH;
        // prefetch next tile into the other buffer (issued BEFORE compute)
        if (t + 1 < NT) {
            unsigned short* b = lds + ((t + 1) & 1) * BUF_USH;
            size_t ka = gA0 + (size_t)(t + 1) * BK;
            size_t kb = gB0 + (size_t)(t + 1) * BK;
            gload16(b + 0*TILE_USH + d0, Fb  + ka);
            gload16(b + 0*TILE_USH + d1, Fb  + ka + gStep);
            gload16(b + 1*TILE_USH + d0, Ub  + ka);
            gload16(b + 1*TILE_USH + d1, Ub  + ka + gStep);
            gload16(b + 2*TILE_USH + d0, Vb  + ka);
            gload16(b + 2*TILE_USH + d1, Vb  + ka + gStep);
            gload16(b + 3*TILE_USH + d0, Wb  + kb);
            gload16(b + 3*TILE_USH + d1, Wb  + kb + gStep);
            gload16(b + 4*TILE_USH + d0, W2b + kb);
            gload16(b + 4*TILE_USH + d1, W2b + kb + gStep);
        }

        short8 aF[4], aU[4], aV[4], bWf[4], bW2f[4];
        #pragma unroll
        for (int m = 0; m < 4; m++) {
            int off = wm * 2048 + m * 512 + aoff;
            aF[m] = *(const short8*)(cbuf + 0*TILE_USH + off);
            aU[m] = *(const short8*)(cbuf + 1*TILE_USH + off);
            aV[m] = *(const short8*)(cbuf + 2*TILE_USH + off);
        }
        #pragma unroll
        for (int n = 0; n < 4; n++) {
            int off = wn * 2048 + n * 512 + aoff;
            bWf[n]  = *(const short8*)(cbuf + 3*TILE_USH + off);
            bW2f[n] = *(const short8*)(cbuf + 4*TILE_USH + off);
        }
        #pragma unroll
        for (int m = 0; m < 4; m++)
            #pragma unroll
            for (int n = 0; n < 4; n++) {
                accL[m][n] = __builtin_amdgcn_mfma_f32_16x16x32_bf16(aF[m], bWf[n],  accL[m][n], 0, 0, 0);
                accA[m][n] = __builtin_amdgcn_mfma_f32_16x16x32_bf16(aU[m], bWf[n],  accA[m][n], 0, 0, 0);
                accA[m][n] = __builtin_amdgcn_mfma_f32_16x16x32_bf16(aV[m], bW2f[n], accA[m][n], 0, 0, 0);
            }

        // barrier drains this iter's prefetch (issued a full compute-phase ago)
        // and orders buffer reuse for the next iteration's prefetch.
        __syncthreads();
    }

    // epilogue
    #pragma unroll
    for (int n = 0; n < 4; n++) {
        int col = bn * BN + wn * 64 + n * 16 + fr;
        if (col < C_CLS) {
            float bv = bias[col];
            #pragma unroll
            for (int m = 0; m < 4; m++) {
                int rbase = bm * BM + wm * 64 + m * 16 + (lane >> 4) * 4;
                #pragma unroll
                for (int j = 0; j < 4; j++) {
                    int row = rbase + j;
                    out_logits[(size_t)row * C_CLS + col] = accL[m][n][j] + bv;
                    aug[(size_t)row * C_PAD + col] = accA[m][n][j] + bv + t3c[row];
                }
            }
        }
    }
}

// ---------------- per-row softmax NLL ---------------------------------------
__global__ __launch_bounds__(256) void softmax_nll(const float* __restrict__ aug,
                                                   const int* __restrict__ labels,
                                                   float* __restrict__ nll) {
    int n = blockIdx.x;
    const float* row = aug + (size_t)n * C_PAD;
    int lane = threadIdx.x & 63, wid = threadIdx.x >> 6;
    __shared__ float sm[4], ss[4];

    float mx = -1e30f;
    for (int c = threadIdx.x; c < C_CLS; c += 256) mx = fmaxf(mx, row[c]);
    for (int off = 32; off; off >>= 1) mx = fmaxf(mx, __shfl_down(mx, off));
    if (lane == 0) sm[wid] = mx;
    __syncthreads();
    mx = fmaxf(fmaxf(sm[0], sm[1]), fmaxf(sm[2], sm[3]));

    float s = 0.f;
    for (int c = threadIdx.x; c < C_CLS; c += 256) s += __expf(row[c] - mx);
    for (int off = 32; off; off >>= 1) s += __shfl_down(s, off);
    if (lane == 0) ss[wid] = s;
    __syncthreads();
    if (threadIdx.x == 0) {
        float tot = ss[0] + ss[1] + ss[2] + ss[3];
        nll[n] = logf(tot) + mx - row[labels[n]];
    }
}

__global__ __launch_bounds__(256) void final_reduce(const float* __restrict__ nll,
                                                    float* __restrict__ out_loss) {
    float s = 0.f;
    for (int i = threadIdx.x; i < N_ROWS; i += 256) s += nll[i];
    for (int off = 32; off; off >>= 1) s += __shfl_down(s, off);
    __shared__ float ss[4];
    int lane = threadIdx.x & 63, wid = threadIdx.x >> 6;
    if (lane == 0) ss[wid] = s;
    __syncthreads();
    if (threadIdx.x == 0)
        out_loss[0] = (ss[0] + ss[1] + ss[2] + ss[3]) / (float)N_ROWS;
}

// ---------------- launch -----------------------------------------------------
extern "C" void kernel_launch(void* const* d_in, const int* in_sizes, int n_in,
                              void* d_out, int out_size, void* d_ws, size_t ws_size,
                              hipStream_t stream) {
    const float* features = (const float*)d_in[0];
    const int*   labels   = (const int*)d_in[1];
    const float* cv       = (const float*)d_in[2];
    const float* ratio    = (const float*)d_in[3];
    const float* weight   = (const float*)d_in[4];
    const float* bias     = (const float*)d_in[5];
    float* out = (float*)d_out;

    char* p = (char*)d_ws;
    unsigned short* Wb  = (unsigned short*)p; p += (size_t)C_PAD * A_DIM * 2;
    unsigned short* W2b = (unsigned short*)p; p += (size_t)C_PAD * A_DIM * 2;
    unsigned short* Fb  = (unsigned short*)p; p += (size_t)N_ROWS * A_DIM * 2;
    unsigned short* Ub  = (unsigned short*)p; p += (size_t)N_ROWS * A_DIM * 2;
    unsigned short* Vb  = (unsigned short*)p; p += (size_t)N_ROWS * A_DIM * 2;
    float* t3c = (float*)p; p += (size_t)N_ROWS * 4;
    float* aug = (float*)p; p += (size_t)N_ROWS * C_PAD * 4;
    float* nllb = (float*)p; p += (size_t)N_ROWS * 4;

    int wprep_blocks = (C_PAD * A_DIM / 8) / 256;  // 1024
    prep_all<<<N_ROWS + wprep_blocks, 256, 0, stream>>>(
        features, cv, weight, labels, ratio, Fb, Ub, Vb, Wb, W2b, t3c);
    gemm_fused<<<(N_ROWS / BM) * (C_PAD / BN), 256, 0, stream>>>(
        Fb, Ub, Vb, Wb, W2b, t3c, bias, out + 1, aug);
    softmax_nll<<<N_ROWS, 256, 0, stream>>>(aug, labels, nllb);
    final_reduce<<<1, 256, 0, stream>>>(nllb, out);
}

// Round 4
// 214.760 us; speedup vs baseline: 1.2599x; 1.1332x over previous
//
#include <hip/hip_runtime.h>
#include <hip/hip_bf16.h>

#define N_ROWS 4096
#define C_CLS  1000
#define C_PAD  1024
#define A_DIM  2048

typedef __attribute__((ext_vector_type(8))) short short8;
typedef __attribute__((ext_vector_type(4))) float f32x4;

__device__ __forceinline__ unsigned short f2bf(float x) {
    unsigned u = __float_as_uint(x);
    unsigned rounding = 0x7fffu + ((u >> 16) & 1u);
    return (unsigned short)((u + rounding) >> 16);
}

__device__ __forceinline__ float bf2f(unsigned short u) {
    return __uint_as_float((unsigned)u << 16);
}

__device__ __forceinline__ unsigned pack2(float a, float b) {
    return (unsigned)f2bf(a) | ((unsigned)f2bf(b) << 16);
}

// async global->LDS, 16B per lane; lds dst is wave-uniform base (HW adds lane*16)
__device__ __forceinline__ void gload16(unsigned short* lds, const unsigned short* g) {
    __builtin_amdgcn_global_load_lds(
        (const __attribute__((address_space(1))) unsigned int*)g,
        (__attribute__((address_space(3))) unsigned int*)lds,
        16, 0, 0);
}

// ---------------- fused prep: blocks [0,4096) per-row A-operands,
//                  blocks [4096,5120) W/W^2 bf16 conversion ------------------
__global__ __launch_bounds__(256) void prep_all(
        const float* __restrict__ F, const float* __restrict__ CV,
        const float* __restrict__ W, const int* __restrict__ labels,
        const float* __restrict__ ratio_p,
        unsigned short* __restrict__ Fb, unsigned short* __restrict__ Ub,
        unsigned short* __restrict__ Vb,
        unsigned short* __restrict__ Wb, unsigned short* __restrict__ W2b,
        float* __restrict__ t3c) {
    int bid = blockIdx.x;
    if (bid >= N_ROWS) {
        int t = (bid - N_ROWS) * 256 + threadIdx.x;
        int a8 = t * 8;
        int c = a8 >> 11;
        int a = a8 & (A_DIM - 1);
        float4 w0 = make_float4(0.f, 0.f, 0.f, 0.f);
        float4 w1 = make_float4(0.f, 0.f, 0.f, 0.f);
        if (c < C_CLS) {
            w0 = *(const float4*)(W + (size_t)c * A_DIM + a);
            w1 = *(const float4*)(W + (size_t)c * A_DIM + a + 4);
        }
        uint4 pw, pw2;
        pw.x  = pack2(w0.x, w0.y);  pw.y  = pack2(w0.z, w0.w);
        pw.z  = pack2(w1.x, w1.y);  pw.w  = pack2(w1.z, w1.w);
        pw2.x = pack2(w0.x*w0.x, w0.y*w0.y);  pw2.y = pack2(w0.z*w0.z, w0.w*w0.w);
        pw2.z = pack2(w1.x*w1.x, w1.y*w1.y);  pw2.w = pack2(w1.z*w1.z, w1.w*w1.w);
        *(uint4*)(Wb  + (size_t)a8) = pw;
        *(uint4*)(W2b + (size_t)a8) = pw2;
        return;
    }
    int n = bid;
    int y = labels[n];
    float ratio = ratio_p[0];
    float hr = 0.5f * ratio;
    const float* frow  = F  + (size_t)n * A_DIM;
    const float* cvrow = CV + (size_t)n * A_DIM;
    const float* wyrow = W  + (size_t)y * A_DIM;
    size_t obase = (size_t)n * A_DIM;

    int a = threadIdx.x * 8;
    float4 f0  = *(const float4*)(frow + a);
    float4 f1  = *(const float4*)(frow + a + 4);
    float4 c0  = *(const float4*)(cvrow + a);
    float4 c1  = *(const float4*)(cvrow + a + 4);
    float4 y0  = *(const float4*)(wyrow + a);
    float4 y1  = *(const float4*)(wyrow + a + 4);

    float s = y0.x*y0.x*c0.x + y0.y*y0.y*c0.y + y0.z*y0.z*c0.z + y0.w*y0.w*c0.w
            + y1.x*y1.x*c1.x + y1.y*y1.y*c1.y + y1.z*y1.z*c1.z + y1.w*y1.w*c1.w;

    uint4 pf, pu, pv;
    pf.x = pack2(f0.x, f0.y);  pf.y = pack2(f0.z, f0.w);
    pf.z = pack2(f1.x, f1.y);  pf.w = pack2(f1.z, f1.w);
    pu.x = pack2(f0.x - ratio*c0.x*y0.x, f0.y - ratio*c0.y*y0.y);
    pu.y = pack2(f0.z - ratio*c0.z*y0.z, f0.w - ratio*c0.w*y0.w);
    pu.z = pack2(f1.x - ratio*c1.x*y1.x, f1.y - ratio*c1.y*y1.y);
    pu.w = pack2(f1.z - ratio*c1.z*y1.z, f1.w - ratio*c1.w*y1.w);
    pv.x = pack2(hr*c0.x, hr*c0.y);  pv.y = pack2(hr*c0.z, hr*c0.w);
    pv.z = pack2(hr*c1.x, hr*c1.y);  pv.w = pack2(hr*c1.z, hr*c1.w);
    *(uint4*)(Fb + obase + a) = pf;
    *(uint4*)(Ub + obase + a) = pu;
    *(uint4*)(Vb + obase + a) = pv;

    for (int off = 32; off; off >>= 1) s += __shfl_down(s, off);
    __shared__ float wsum[4];
    int lane = threadIdx.x & 63, wid = threadIdx.x >> 6;
    if (lane == 0) wsum[wid] = s;
    __syncthreads();
    if (threadIdx.x == 0)
        t3c[n] = hr * (wsum[0] + wsum[1] + wsum[2] + wsum[3]);
}

// ---------------- fused triple-GEMM: logits(f32) + aug(bf16) ----------------
#define BM 128
#define BN 64
#define BK 32
#define TILE_A (BM * BK)              // 4096 ushorts
#define TILE_B (BN * BK)              // 2048 ushorts
#define BUF_USH (3 * TILE_A + 2 * TILE_B)   // 16384 ushorts = 32KB
#define NT (A_DIM / BK)               // 64 K-steps

__global__ __launch_bounds__(256, 2) void gemm_fused(
        const unsigned short* __restrict__ Fb, const unsigned short* __restrict__ Ub,
        const unsigned short* __restrict__ Vb, const unsigned short* __restrict__ Wb,
        const unsigned short* __restrict__ W2b,
        const float* __restrict__ t3c, const float* __restrict__ bias,
        float* __restrict__ out_logits, unsigned short* __restrict__ aug) {
    __shared__ unsigned short lds[2 * BUF_USH];   // 64 KiB double-buffered

    // grid 512 = 32 bm x 16 bn; XCD x owns bn pair {2x,2x+1} (B L2-resident)
    int bid = blockIdx.x;
    int xcd = bid & 7, idx = bid >> 3;            // idx in [0,64)
    int bn = (xcd << 1) | (idx & 1);              // [0,16)
    int bm = idx >> 1;                            // [0,32)

    int tid = threadIdx.x;
    int lane = tid & 63, wid = tid >> 6;
    int wm = wid >> 1, wn = wid & 1;              // 2x2 waves; wave tile 64x32

    // staging: per issue, wave covers 16 rows x 32 cols (1KB)
    int srow = lane >> 2;                                   // 0..15
    int scs  = ((lane & 3) * 8) ^ (((srow >> 1) & 3) << 3); // swizzled col
    int r0 = wid * 16 + srow;
    size_t gA0 = (size_t)(bm * BM + r0) * A_DIM + scs;
    size_t gB0 = (size_t)(bn * BN + r0) * A_DIM + scs;
    const size_t gStep = (size_t)64 * A_DIM;
    int d0 = wid * 512;           // LDS chunk (ushorts), rows [0,64)
    int d1 = 2048 + wid * 512;    // rows [64,128) for A tiles

    // fragment read addressing (same XOR -> conflict-free)
    int fr = lane & 15;
    int kof = ((lane >> 4) * 8) ^ (((fr >> 1) & 3) << 3);
    int aoff = fr * BK + kof;

    f32x4 accL[4][2] = {};
    f32x4 accA[4][2] = {};

    // prologue: stage tile 0 into buffer 0
    {
        unsigned short* b = lds;
        gload16(b + 0*TILE_A + d0, Fb + gA0);
        gload16(b + 0*TILE_A + d1, Fb + gA0 + gStep);
        gload16(b + 1*TILE_A + d0, Ub + gA0);
        gload16(b + 1*TILE_A + d1, Ub + gA0 + gStep);
        gload16(b + 2*TILE_A + d0, Vb + gA0);
        gload16(b + 2*TILE_A + d1, Vb + gA0 + gStep);
        gload16(b + 3*TILE_A + d0,          Wb  + gB0);
        gload16(b + 3*TILE_A + TILE_B + d0, W2b + gB0);
    }
    __syncthreads();

    for (int t = 0; t < NT; t++) {
        unsigned short* cbuf = lds + (t & 1) * BUF_USH;
        if (t + 1 < NT) {
            unsigned short* b = lds + ((t + 1) & 1) * BUF_USH;
            size_t ka = gA0 + (size_t)(t + 1) * BK;
            size_t kb = gB0 + (size_t)(t + 1) * BK;
            gload16(b + 0*TILE_A + d0, Fb + ka);
            gload16(b + 0*TILE_A + d1, Fb + ka + gStep);
            gload16(b + 1*TILE_A + d0, Ub + ka);
            gload16(b + 1*TILE_A + d1, Ub + ka + gStep);
            gload16(b + 2*TILE_A + d0, Vb + ka);
            gload16(b + 2*TILE_A + d1, Vb + ka + gStep);
            gload16(b + 3*TILE_A + d0,          Wb  + kb);
            gload16(b + 3*TILE_A + TILE_B + d0, W2b + kb);
        }

        short8 aF[4], aU[4], aV[4], bWf[2], bW2f[2];
        #pragma unroll
        for (int m = 0; m < 4; m++) {
            int off = wm * 2048 + m * 512 + aoff;
            aF[m] = *(const short8*)(cbuf + 0*TILE_A + off);
            aU[m] = *(const short8*)(cbuf + 1*TILE_A + off);
            aV[m] = *(const short8*)(cbuf + 2*TILE_A + off);
        }
        #pragma unroll
        for (int n = 0; n < 2; n++) {
            int off = wn * 1024 + n * 512 + aoff;
            bWf[n]  = *(const short8*)(cbuf + 3*TILE_A + off);
            bW2f[n] = *(const short8*)(cbuf + 3*TILE_A + TILE_B + off);
        }
        #pragma unroll
        for (int m = 0; m < 4; m++)
            #pragma unroll
            for (int n = 0; n < 2; n++) {
                accL[m][n] = __builtin_amdgcn_mfma_f32_16x16x32_bf16(aF[m], bWf[n],  accL[m][n], 0, 0, 0);
                accA[m][n] = __builtin_amdgcn_mfma_f32_16x16x32_bf16(aU[m], bWf[n],  accA[m][n], 0, 0, 0);
                accA[m][n] = __builtin_amdgcn_mfma_f32_16x16x32_bf16(aV[m], bW2f[n], accA[m][n], 0, 0, 0);
            }

        __syncthreads();
    }

    // epilogue: logits f32 -> d_out+1; aug bf16 -> ws
    #pragma unroll
    for (int n = 0; n < 2; n++) {
        int col = bn * BN + wn * 32 + n * 16 + fr;
        if (col < C_CLS) {
            float bv = bias[col];
            #pragma unroll
            for (int m = 0; m < 4; m++) {
                int rbase = bm * BM + wm * 64 + m * 16 + (lane >> 4) * 4;
                #pragma unroll
                for (int j = 0; j < 4; j++) {
                    int row = rbase + j;
                    out_logits[(size_t)row * C_CLS + col] = accL[m][n][j] + bv;
                    aug[(size_t)row * C_PAD + col] = f2bf(accA[m][n][j] + bv + t3c[row]);
                }
            }
        }
    }
}

// ---------------- per-row softmax NLL (bf16 aug) ----------------------------
__global__ __launch_bounds__(256) void softmax_nll(const unsigned short* __restrict__ aug,
                                                   const int* __restrict__ labels,
                                                   float* __restrict__ nll) {
    int n = blockIdx.x;
    const unsigned short* row = aug + (size_t)n * C_PAD;
    int tid = threadIdx.x;
    int lane = tid & 63, wid = tid >> 6;
    __shared__ float sm[4], ss[4];

    float v[8];
    bool act = tid < (C_CLS / 8);    // 125 active threads, 8 elems each
    float mx = -1e30f;
    if (act) {
        short8 r8 = *(const short8*)(row + tid * 8);
        #pragma unroll
        for (int j = 0; j < 8; j++) {
            v[j] = bf2f((unsigned short)r8[j]);
            mx = fmaxf(mx, v[j]);
        }
    }
    for (int off = 32; off; off >>= 1) mx = fmaxf(mx, __shfl_down(mx, off));
    if (lane == 0) sm[wid] = mx;
    __syncthreads();
    mx = fmaxf(fmaxf(sm[0], sm[1]), fmaxf(sm[2], sm[3]));

    float s = 0.f;
    if (act) {
        #pragma unroll
        for (int j = 0; j < 8; j++) s += __expf(v[j] - mx);
    }
    for (int off = 32; off; off >>= 1) s += __shfl_down(s, off);
    if (lane == 0) ss[wid] = s;
    __syncthreads();
    if (tid == 0) {
        float tot = ss[0] + ss[1] + ss[2] + ss[3];
        nll[n] = logf(tot) + mx - bf2f(row[labels[n]]);
    }
}

__global__ __launch_bounds__(256) void final_reduce(const float* __restrict__ nll,
                                                    float* __restrict__ out_loss) {
    float s = 0.f;
    for (int i = threadIdx.x; i < N_ROWS; i += 256) s += nll[i];
    for (int off = 32; off; off >>= 1) s += __shfl_down(s, off);
    __shared__ float ss[4];
    int lane = threadIdx.x & 63, wid = threadIdx.x >> 6;
    if (lane == 0) ss[wid] = s;
    __syncthreads();
    if (threadIdx.x == 0)
        out_loss[0] = (ss[0] + ss[1] + ss[2] + ss[3]) / (float)N_ROWS;
}

// ---------------- launch -----------------------------------------------------
extern "C" void kernel_launch(void* const* d_in, const int* in_sizes, int n_in,
                              void* d_out, int out_size, void* d_ws, size_t ws_size,
                              hipStream_t stream) {
    const float* features = (const float*)d_in[0];
    const int*   labels   = (const int*)d_in[1];
    const float* cv       = (const float*)d_in[2];
    const float* ratio    = (const float*)d_in[3];
    const float* weight   = (const float*)d_in[4];
    const float* bias     = (const float*)d_in[5];
    float* out = (float*)d_out;

    char* p = (char*)d_ws;
    unsigned short* Wb  = (unsigned short*)p; p += (size_t)C_PAD * A_DIM * 2;
    unsigned short* W2b = (unsigned short*)p; p += (size_t)C_PAD * A_DIM * 2;
    unsigned short* Fb  = (unsigned short*)p; p += (size_t)N_ROWS * A_DIM * 2;
    unsigned short* Ub  = (unsigned short*)p; p += (size_t)N_ROWS * A_DIM * 2;
    unsigned short* Vb  = (unsigned short*)p; p += (size_t)N_ROWS * A_DIM * 2;
    float* t3c = (float*)p; p += (size_t)N_ROWS * 4;
    unsigned short* aug = (unsigned short*)p; p += (size_t)N_ROWS * C_PAD * 2;
    float* nllb = (float*)p; p += (size_t)N_ROWS * 4;

    int wprep_blocks = (C_PAD * A_DIM / 8) / 256;  // 1024
    prep_all<<<N_ROWS + wprep_blocks, 256, 0, stream>>>(
        features, cv, weight, labels, ratio, Fb, Ub, Vb, Wb, W2b, t3c);
    gemm_fused<<<(N_ROWS / BM) * (C_PAD / BN), 256, 0, stream>>>(
        Fb, Ub, Vb, Wb, W2b, t3c, bias, out + 1, aug);
    softmax_nll<<<N_ROWS, 256, 0, stream>>>(aug, labels, nllb);
    final_reduce<<<1, 256, 0, stream>>>(nllb, out);
}